// Round 14
// baseline (171.584 us; speedup 1.0000x reference)
//
#include <hip/hip_runtime.h>

typedef float f32x4 __attribute__((ext_vector_type(4)));
typedef __bf16 bf16x8 __attribute__((ext_vector_type(8)));
typedef unsigned int u32x4 __attribute__((ext_vector_type(4)));
typedef unsigned int u32x2 __attribute__((ext_vector_type(2)));

#define TT 32   // atoms per block tile (20000 = 625 * 32, no tail)

// packed bf16 weight planes in d_ws after dEdD (ushort element offsets)
#define PW1_HI   0
#define PW1_LO   8192
#define PW2_HI   16384
#define PW2_LO   32768
#define PW2T_HI  49152
#define PW2T_LO  65536
#define PW1T_HI  81920
#define PW1T_LO  90112
#define PW_SLOTS 49152

__global__ void zero_kernel(float* __restrict__ p, int n) {
    int i = blockIdx.x * blockDim.x + threadIdx.x;
    if (i < n) p[i] = 0.f;
}

__device__ __forceinline__ void bf16split(float x, unsigned short& hi, unsigned short& lo) {
    unsigned u = __float_as_uint(x);
    unsigned r = (u + 0x7FFFu + ((u >> 16) & 1u)) >> 16;   // RNE to bf16
    hi = (unsigned short)r;
    float hf = __uint_as_float(r << 16);
    unsigned u2 = __float_as_uint(x - hf);                 // exact residual
    unsigned r2 = (u2 + 0x7FFFu + ((u2 >> 16) & 1u)) >> 16;
    lo = (unsigned short)r2;
}

__device__ __forceinline__ void split2(float a, float b, unsigned& hw, unsigned& lw) {
    unsigned ua = __float_as_uint(a);
    unsigned ra = (ua + 0x7FFFu + ((ua >> 16) & 1u)) >> 16;
    unsigned ua2 = __float_as_uint(a - __uint_as_float(ra << 16));
    unsigned la = (ua2 + 0x7FFFu + ((ua2 >> 16) & 1u)) >> 16;
    unsigned ub = __float_as_uint(b);
    unsigned rb = (ub + 0x7FFFu + ((ub >> 16) & 1u)) >> 16;
    unsigned ub2 = __float_as_uint(b - __uint_as_float(rb << 16));
    unsigned lb = (ub2 + 0x7FFFu + ((ub2 >> 16) & 1u)) >> 16;
    hw = ra | (rb << 16);
    lw = la | (lb << 16);
}

// ---------------- weight pre-pack: fragment-ordered bf16 hi/lo planes ----------------
__global__ void pack_weights(const float* __restrict__ W1, const float* __restrict__ W2,
                             unsigned short* __restrict__ pw) {
    int s = blockIdx.x * blockDim.x + threadIdx.x;
    if (s >= PW_SLOTS) return;
    int slot, NS, hiOff, loOff; const float* src; bool tr;
    if (s < 8192)       { slot = s;         NS = 8; hiOff = PW1_HI;  loOff = PW1_LO;  tr = false; src = W1; }
    else if (s < 24576) { slot = s - 8192;  NS = 8; hiOff = PW2_HI;  loOff = PW2_LO;  tr = false; src = W2; }
    else if (s < 40960) { slot = s - 24576; NS = 8; hiOff = PW2T_HI; loOff = PW2T_LO; tr = true;  src = W2; }
    else                { slot = s - 40960; NS = 4; hiOff = PW1T_HI; loOff = PW1T_LO; tr = true;  src = W1; }
    int j = slot & 7, lane = (slot >> 3) & 63, rest = slot >> 9;
    int ns = rest % NS, ks = rest / NS;
    int k = ks * 32 + ((lane >> 4) & 3) * 8 + j;
    int n = ns * 16 + (lane & 15);
    float v = tr ? src[n * 128 + k] : src[k * 128 + n];
    unsigned short hi, lo;
    bf16split(v, hi, lo);
    pw[hiOff + slot] = hi;
    pw[loOff + slot] = lo;
}

// ---------------- fused MLP fwd+bwd via MFMA ----------------
// R13 lesson: latency-bound at 2.4 waves/SIMD (spill was incidental). This
// version: 8 waves/block (4-way n-split x 2 msub) -> 5000 waves (~4.9/SIMD
// supply), and activations live in LDS as PRE-SPLIT bf16 hi/lo planes in
// MFMA-fragment order: A-frag load = two conflict-free ds_read_b128, no VALU,
// no hoisted 32-reg frag array -> small reg footprint, 2 blocks/CU at the
// (512,4) 128-reg cap without spill.
// Plane layout (ushort idx): ((ks*2 + msub)*64 + lane)*8 + j,
// element (m,k): msub=m>>4, lane=(m&15)+((k>>3)&3)*16, j=k&7, ks=k>>5.
__global__ __launch_bounds__(512, 4) void mlp_mfma(
    const float* __restrict__ x,
    const float* __restrict__ b1, const float* __restrict__ b2,
    const float* __restrict__ W3, const float* __restrict__ b3,
    const int* __restrict__ indices,
    const unsigned short* __restrict__ pw,
    float* __restrict__ energy, float* __restrict__ dEdD, int natoms)
{
    __shared__ __align__(16) unsigned short xsH[2 * 2 * 64 * 8];   // 4 KB  (K=64)
    __shared__ __align__(16) unsigned short xsL[2 * 2 * 64 * 8];   // 4 KB
    __shared__ __align__(16) unsigned short h1H[4 * 2 * 64 * 8];   // 8 KB  (K=128), later dz1
    __shared__ __align__(16) unsigned short h1L[4 * 2 * 64 * 8];   // 8 KB
    __shared__ __align__(16) unsigned short g2H[4 * 2 * 64 * 8];   // 8 KB
    __shared__ __align__(16) unsigned short g2L[4 * 2 * 64 * 8];   // 8 KB

    const int tid = threadIdx.x;
    const int l   = tid & 63;
    const int w   = tid >> 6;        // 0..7
    const int col = l & 15;
    const int rg  = l >> 4;          // 0..3
    const int msub = w >> 2;         // 0..1  (16-atom row tile)
    const int nq   = w & 3;          // 0..3  (n-quarter)
    const int a0 = blockIdx.x * TT;

    // ---- stage x into frag-order bf16 hi/lo planes (1 f32x4 chunk/thread) ----
    {
        int r = tid >> 4, c4 = tid & 15;        // row 0..31, chunk 0..15 (4 d's)
        int a = a0 + r;
        f32x4 v = {0.f, 0.f, 0.f, 0.f};
        if (a < natoms) v = *(const f32x4*)(x + (size_t)a * 64 + c4 * 4);
        unsigned h01, l01, h23, l23;
        split2(v[0], v[1], h01, l01);
        split2(v[2], v[3], h23, l23);
        int ks = c4 >> 3;
        int lane2 = (r & 15) + (((c4 >> 1) & 3) << 4);
        int j2 = (c4 * 4) & 7;                   // 0 or 4
        int off = (((ks * 2 + (r >> 4)) * 64 + lane2) << 3) + j2;
        *(u32x2*)(xsH + off) = (u32x2){h01, h23};
        *(u32x2*)(xsL + off) = (u32x2){l01, l23};
    }
    __syncthreads();

    auto loadAB = [&](const unsigned short* pH, const unsigned short* pL,
                      int ks, bf16x8& ah, bf16x8& al) {
        int off = ((ks * 2 + msub) * 64 + l) << 3;
        ah = __builtin_bit_cast(bf16x8, *(const u32x4*)(pH + off));
        al = __builtin_bit_cast(bf16x8, *(const u32x4*)(pL + off));
    };
    auto loadB = [&](int hiOff, int loOff, int NS, int ks, int nsub, bf16x8& bh, bf16x8& bl) {
        int idx = ((ks * NS + nsub) * 64 + l) << 3;
        bh = __builtin_bit_cast(bf16x8, *(const u32x4*)(pw + hiOff + idx));
        bl = __builtin_bit_cast(bf16x8, *(const u32x4*)(pw + loOff + idx));
    };
    // destination ushort offset for element (m-row local rg*4+r2, n)
    auto dstOff = [&](int r2, int nsub, int cl) {
        int ks2 = nsub >> 1;
        int lane2 = (rg * 4 + r2) + (((nsub * 2 + (cl >> 3)) & 3) << 4);
        return (((ks2 * 2 + msub) * 64 + lane2) << 3) + (cl & 7);
    };

    // ---- GEMM1: z1 = X@W1 + b1; h1 = sigm -> h1 planes ----
    #pragma unroll
    for (int ns = 0; ns < 2; ++ns) {
        int nsub = nq * 2 + ns, n0 = nsub * 16;
        float bv = b1[n0 + col];
        f32x4 acc = {bv, bv, bv, bv};
        #pragma unroll
        for (int ks = 0; ks < 2; ++ks) {
            bf16x8 ah, al, bh, bl;
            loadAB(xsH, xsL, ks, ah, al);
            loadB(PW1_HI, PW1_LO, 8, ks, nsub, bh, bl);
            acc = __builtin_amdgcn_mfma_f32_16x16x32_bf16(ah, bh, acc, 0, 0, 0);
            acc = __builtin_amdgcn_mfma_f32_16x16x32_bf16(al, bh, acc, 0, 0, 0);
            acc = __builtin_amdgcn_mfma_f32_16x16x32_bf16(ah, bl, acc, 0, 0, 0);
        }
        #pragma unroll
        for (int r2 = 0; r2 < 4; ++r2) {
            float h = 1.f / (1.f + expf(-acc[r2]));
            unsigned short hi, lo; bf16split(h, hi, lo);
            int off = dstOff(r2, nsub, col);
            h1H[off] = hi; h1L[off] = lo;
        }
    }
    __syncthreads();

    // ---- GEMM2: z2 = h1@W2 + b2; h2, energy, g2 -> g2 planes ----
    float e[4] = {0.f, 0.f, 0.f, 0.f};
    #pragma unroll
    for (int ns = 0; ns < 2; ++ns) {
        int nsub = nq * 2 + ns, n0 = nsub * 16;
        float bv = b2[n0 + col];
        f32x4 acc = {bv, bv, bv, bv};
        #pragma unroll
        for (int ks = 0; ks < 4; ++ks) {
            bf16x8 ah, al, bh, bl;
            loadAB(h1H, h1L, ks, ah, al);
            loadB(PW2_HI, PW2_LO, 8, ks, nsub, bh, bl);
            acc = __builtin_amdgcn_mfma_f32_16x16x32_bf16(ah, bh, acc, 0, 0, 0);
            acc = __builtin_amdgcn_mfma_f32_16x16x32_bf16(al, bh, acc, 0, 0, 0);
            acc = __builtin_amdgcn_mfma_f32_16x16x32_bf16(ah, bl, acc, 0, 0, 0);
        }
        float w3v = W3[n0 + col];
        #pragma unroll
        for (int r2 = 0; r2 < 4; ++r2) {
            float h2 = 1.f / (1.f + expf(-acc[r2]));
            e[r2] += h2 * w3v;
            float g = w3v * h2 * (1.f - h2);
            unsigned short hi, lo; bf16split(g, hi, lo);
            int off = dstOff(r2, nsub, col);
            g2H[off] = hi; g2L[off] = lo;
        }
    }
    #pragma unroll
    for (int r2 = 0; r2 < 4; ++r2) {
        float v = e[r2];
        v += __shfl_xor(v, 1); v += __shfl_xor(v, 2);
        v += __shfl_xor(v, 4); v += __shfl_xor(v, 8);
        e[r2] = v;
    }
    if (col == 0) {
        float b3v = (nq == 0) ? b3[0] : 0.f;
        #pragma unroll
        for (int r2 = 0; r2 < 4; ++r2) {
            int a = a0 + msub * 16 + rg * 4 + r2;
            if (a < natoms) atomicAdd(&energy[indices[a]], e[r2] + b3v);
        }
    }
    __syncthreads();

    // ---- GEMM3: dh1 = g2@W2^T; dz1 = dh1*h1*(1-h1) -> overwrite h1 planes ----
    #pragma unroll
    for (int ns = 0; ns < 2; ++ns) {
        int nsub = nq * 2 + ns;
        f32x4 acc = {0.f, 0.f, 0.f, 0.f};
        #pragma unroll
        for (int ks = 0; ks < 4; ++ks) {
            bf16x8 ah, al, bh, bl;
            loadAB(g2H, g2L, ks, ah, al);
            loadB(PW2T_HI, PW2T_LO, 8, ks, nsub, bh, bl);
            acc = __builtin_amdgcn_mfma_f32_16x16x32_bf16(ah, bh, acc, 0, 0, 0);
            acc = __builtin_amdgcn_mfma_f32_16x16x32_bf16(al, bh, acc, 0, 0, 0);
            acc = __builtin_amdgcn_mfma_f32_16x16x32_bf16(ah, bl, acc, 0, 0, 0);
        }
        #pragma unroll
        for (int r2 = 0; r2 < 4; ++r2) {
            int off = dstOff(r2, nsub, col);
            float h = __uint_as_float((unsigned)h1H[off] << 16)
                    + __uint_as_float((unsigned)h1L[off] << 16);
            float dz = acc[r2] * h * (1.f - h);
            unsigned short hi, lo; bf16split(dz, hi, lo);
            h1H[off] = hi; h1L[off] = lo;
        }
    }
    __syncthreads();

    // ---- GEMM4: dEdD = dz1@W1^T ----
    {
        int nsub = nq, n0 = nq * 16;
        f32x4 acc = {0.f, 0.f, 0.f, 0.f};
        #pragma unroll
        for (int ks = 0; ks < 4; ++ks) {
            bf16x8 ah, al, bh, bl;
            loadAB(h1H, h1L, ks, ah, al);
            loadB(PW1T_HI, PW1T_LO, 4, ks, nsub, bh, bl);
            acc = __builtin_amdgcn_mfma_f32_16x16x32_bf16(ah, bh, acc, 0, 0, 0);
            acc = __builtin_amdgcn_mfma_f32_16x16x32_bf16(al, bh, acc, 0, 0, 0);
            acc = __builtin_amdgcn_mfma_f32_16x16x32_bf16(ah, bl, acc, 0, 0, 0);
        }
        #pragma unroll
        for (int r2 = 0; r2 < 4; ++r2) {
            int a = a0 + msub * 16 + rg * 4 + r2;
            if (a < natoms) dEdD[(size_t)a * 64 + n0 + col] = acc[r2];
        }
    }
}

// ---------------- force accumulation (unchanged, proven) ----------------
__global__ __launch_bounds__(256) void force_kernel(
    const float* __restrict__ xd,
    const int* __restrict__ unique_i, const int* __restrict__ unique_j,
    const float* __restrict__ dEdD,
    float* __restrict__ forces, int nderiv)
{
    const int tid = threadIdx.x;
    const int lane = tid & 63;
    const int wib = tid >> 6;
    const int gwave = blockIdx.x * 4 + wib;
    const int nwaves = gridDim.x * 4;
    const int sub = lane >> 4;
    const int t = lane & 15;
    const int ngroups = (nderiv + 3) >> 2;

    for (int g = gwave; g < ngroups; g += nwaves) {
        const int r = g * 4 + sub;
        float p = 0.f;
        int jdst = 0, ax = 0;
        const bool valid = (r < nderiv);
        if (valid) {
            const int ai = unique_i[r];
            const float4 v = ((const float4*)(xd   + (size_t)r  * 64))[t];
            const float4 wv = ((const float4*)(dEdD + (size_t)ai * 64))[t];
            p = v.x * wv.x + v.y * wv.y + v.z * wv.z + v.w * wv.w;
            jdst = unique_j[r];
            ax = r % 3;   // axis = tile([0,1,2]) by construction
        }
        p += __shfl_xor(p, 1);
        p += __shfl_xor(p, 2);
        p += __shfl_xor(p, 4);
        p += __shfl_xor(p, 8);
        if (t == 0 && valid) atomicAdd(&forces[jdst * 3 + ax], p);
    }
}

extern "C" void kernel_launch(void* const* d_in, const int* in_sizes, int n_in,
                              void* d_out, int out_size, void* d_ws, size_t ws_size,
                              hipStream_t stream) {
    const float* x        = (const float*)d_in[0];
    const float* xd       = (const float*)d_in[1];
    const int*   indices  = (const int*)d_in[2];
    const int*   unique_i = (const int*)d_in[6];
    const int*   unique_j = (const int*)d_in[7];
    const float* W1       = (const float*)d_in[8];
    const float* b1       = (const float*)d_in[9];
    const float* W2       = (const float*)d_in[10];
    const float* b2       = (const float*)d_in[11];
    const float* W3       = (const float*)d_in[12];
    const float* b3       = (const float*)d_in[13];

    const int natoms = in_sizes[2];
    const int nconf  = in_sizes[3];
    const int nderiv = in_sizes[6];

    float* out    = (float*)d_out;
    float* energy = out;
    float* forces = out + nconf;
    float* dEdD   = (float*)d_ws;
    unsigned short* pw = (unsigned short*)((char*)d_ws + (size_t)natoms * 64 * 4);

    const int ntiles = (natoms + TT - 1) / TT;

    zero_kernel<<<(out_size + 255) / 256, 256, 0, stream>>>(out, out_size);
    pack_weights<<<(PW_SLOTS + 255) / 256, 256, 0, stream>>>(W1, W2, pw);
    mlp_mfma<<<ntiles, 512, 0, stream>>>(x, b1, b2, W3, b3, indices, pw,
                                         energy, dEdD, natoms);
    force_kernel<<<2048, 256, 0, stream>>>(xd, unique_i, unique_j, dEdD,
                                           forces, nderiv);
}